// Round 2
// baseline (371.317 us; speedup 1.0000x reference)
//
#include <hip/hip_runtime.h>
#include <hip/hip_bf16.h>

// Problem constants (match reference)
#define BB 32
#define SS 1024
#define EE 1024
#define AA 1024
// M = BB*SS = 32768

typedef __attribute__((ext_vector_type(8))) short short8;
typedef __attribute__((ext_vector_type(8))) unsigned short ushort8;
typedef __attribute__((ext_vector_type(4))) float f32x4;

__device__ inline unsigned short f2bf(float f) {
    __hip_bfloat16 h = __float2bfloat16(f);
    union { __hip_bfloat16 h; unsigned short s; } u;
    u.h = h;
    return u.s;
}

__device__ inline float fast_tanh(float x) {
    // tanh(x) = 1 - 2/(e^{2x}+1); exp via v_exp, rcp via v_rcp.
    float e2 = __expf(2.0f * x);
    return 1.0f - 2.0f * __builtin_amdgcn_rcpf(e2 + 1.0f);
}

// ---------------------------------------------------------------------------
// Kernel 0: cast W_enc (f32 [A][E]) -> bf16 ws copy. 1M elems, 4/thread.
__global__ __launch_bounds__(256) void cast_w_kernel(const float* __restrict__ W,
                                                     unsigned short* __restrict__ Wbf) {
    int i = (blockIdx.x * 256 + threadIdx.x) * 4;
    f32x4 v = *(const f32x4*)(W + i);
    unsigned short o0 = f2bf(v[0]), o1 = f2bf(v[1]), o2 = f2bf(v[2]), o3 = f2bf(v[3]);
    // 8-byte store
    union { unsigned short s[4]; unsigned long long q; } u;
    u.s[0] = o0; u.s[1] = o1; u.s[2] = o2; u.s[3] = o3;
    *(unsigned long long*)(Wbf + i) = u.q;
}

// ---------------------------------------------------------------------------
// Kernel 1: dec_full[b][a] = sum_d dec_state[b][d]*W_dec[a][d] + b_enc[a]
// grid (16, 32), block 256. 4 threads cooperate per (b,a) dot (coalesced W).
__global__ __launch_bounds__(256) void dec_full_kernel(const float* __restrict__ dec_state,
                                                       const float* __restrict__ W_dec,
                                                       const float* __restrict__ b_enc,
                                                       float* __restrict__ dec_full) {
    int tid = threadIdx.x;
    int a = blockIdx.x * 64 + (tid >> 2);
    int q = tid & 3;
    int b = blockIdx.y;
    const float* wrow = W_dec + (size_t)a * 1024;
    const float* xrow = dec_state + (size_t)b * 1024;
    float acc = 0.0f;
#pragma unroll 8
    for (int i = 0; i < 64; ++i) {
        int d = q * 4 + i * 16;
        f32x4 w = *(const f32x4*)(wrow + d);
        f32x4 x = *(const f32x4*)(xrow + d);
        acc += w[0] * x[0] + w[1] * x[1] + w[2] * x[2] + w[3] * x[3];
    }
    acc += __shfl_xor(acc, 1);
    acc += __shfl_xor(acc, 2);
    if (q == 0) dec_full[(size_t)b * 1024 + a] = acc + b_enc[a];
}

// ---------------------------------------------------------------------------
// Kernel 2: fused energy GEMM.
// energy[m] += sum_n tanh( enc[m,:]·W_enc[n,:] + dec_full[b][n] ) * w_attn[n]
// 128x128 tile, BK=32, 4 waves (2x2), 16x16x32 bf16 MFMA, 4x4 frags/wave.
// enc is cast f32->bf16 inline during staging; W_enc pre-cast to bf16 in ws.
__global__ __launch_bounds__(256) void energy_gemm(const float* __restrict__ enc,
                                                   const unsigned short* __restrict__ Wbf,
                                                   const float* __restrict__ dec_full,
                                                   const float* __restrict__ w_attn,
                                                   float* __restrict__ energy) {
    __shared__ unsigned short As[128 * 32];
    __shared__ unsigned short Bs[128 * 32];

    // XCD-aware swizzle: keep the 8 col-blocks of one row-panel on one XCD
    // (enc panel becomes L2-resident; W_enc bf16 (2MB) is L2-resident anyway).
    int id = blockIdx.x;                 // 2048 = 256 row-blocks x 8 col-blocks
    int wid = (id & 7) * 256 + (id >> 3);
    int br = wid >> 3, bc = wid & 7;
    int m0 = br * 128, n0 = bc * 128;

    int tid = threadIdx.x;
    int lane = tid & 63, w = tid >> 6;
    int wr = w >> 1, wc = w & 1;        // wave tile origin (wr*64, wc*64)
    int l15 = lane & 15, lg = lane >> 4;

    f32x4 acc[4][4] = {};

    int srow = tid >> 1;                 // 0..127
    int shalf = tid & 1;                 // 16 elems each
    const float* encp = enc + (size_t)(m0 + srow) * 1024 + shalf * 16;
    const unsigned short* wbp = Wbf + (size_t)(n0 + srow) * 1024 + shalf * 16;
    unsigned short* asw = &As[srow * 32 + shalf * 16];
    unsigned short* bsw = &Bs[srow * 32 + shalf * 16];

    for (int k0 = 0; k0 < 1024; k0 += 32) {
        // global loads for this K-step (issued before the barrier)
        f32x4 t0 = *(const f32x4*)(encp + k0);
        f32x4 t1 = *(const f32x4*)(encp + k0 + 4);
        f32x4 t2 = *(const f32x4*)(encp + k0 + 8);
        f32x4 t3 = *(const f32x4*)(encp + k0 + 12);
        ushort8 wb0 = *(const ushort8*)(wbp + k0);
        ushort8 wb1 = *(const ushort8*)(wbp + k0 + 8);

        __syncthreads();                 // prior iteration's LDS reads done
        ushort8 pa, pb;
#pragma unroll
        for (int j = 0; j < 4; ++j) {
            pa[j]     = f2bf(t0[j]);
            pa[j + 4] = f2bf(t1[j]);
            pb[j]     = f2bf(t2[j]);
            pb[j + 4] = f2bf(t3[j]);
        }
        *(ushort8*)asw       = pa;
        *(ushort8*)(asw + 8) = pb;
        *(ushort8*)bsw       = wb0;
        *(ushort8*)(bsw + 8) = wb1;
        __syncthreads();

        short8 af[4], bfr[4];
#pragma unroll
        for (int mi = 0; mi < 4; ++mi)
            af[mi] = *(const short8*)&As[(wr * 64 + mi * 16 + l15) * 32 + lg * 8];
#pragma unroll
        for (int ni = 0; ni < 4; ++ni)
            bfr[ni] = *(const short8*)&Bs[(wc * 64 + ni * 16 + l15) * 32 + lg * 8];
#pragma unroll
        for (int mi = 0; mi < 4; ++mi)
#pragma unroll
            for (int ni = 0; ni < 4; ++ni)
                acc[mi][ni] = __builtin_amdgcn_mfma_f32_16x16x32_bf16(
                    af[mi], bfr[ni], acc[mi][ni], 0, 0, 0);
    }

    // Epilogue: tanh(acc + dec_full) * w_attn, reduce over n, atomic into energy.
    int b = m0 >> 10;                    // BM=128 divides S=1024: b constant/block
    float wv[4], dv[4];
#pragma unroll
    for (int ni = 0; ni < 4; ++ni) {
        int n = n0 + wc * 64 + ni * 16 + l15;
        wv[ni] = w_attn[n];
        dv[ni] = dec_full[(size_t)b * 1024 + n];
    }
#pragma unroll
    for (int mi = 0; mi < 4; ++mi) {
#pragma unroll
        for (int r = 0; r < 4; ++r) {
            float p = 0.0f;
#pragma unroll
            for (int ni = 0; ni < 4; ++ni)
                p += fast_tanh(acc[mi][ni][r] + dv[ni]) * wv[ni];
            // reduce across the 16 col-lanes (within each 16-lane group)
            p += __shfl_xor(p, 1);
            p += __shfl_xor(p, 2);
            p += __shfl_xor(p, 4);
            p += __shfl_xor(p, 8);
            if (l15 == 0) {
                int m = m0 + wr * 64 + mi * 16 + lg * 4 + r;
                atomicAdd(&energy[m], p);
            }
        }
    }
}

// ---------------------------------------------------------------------------
// Kernel 3: masked softmax + renorm (identical to softmax->*mask->renorm).
// One block per batch row. 256 threads, 4 elems each.
__global__ __launch_bounds__(256) void softmax_mask_kernel(const float* __restrict__ energy,
                                                           const float* __restrict__ mask,
                                                           float* __restrict__ alpha) {
    int b = blockIdx.x;
    int tid = threadIdx.x;
    int lane = tid & 63, wv = tid >> 6;
    __shared__ float red[4];

    float e[4];
#pragma unroll
    for (int i = 0; i < 4; ++i) e[i] = energy[b * 1024 + tid + i * 256];

    float mx = fmaxf(fmaxf(e[0], e[1]), fmaxf(e[2], e[3]));
#pragma unroll
    for (int off = 1; off < 64; off <<= 1) mx = fmaxf(mx, __shfl_xor(mx, off));
    if (lane == 0) red[wv] = mx;
    __syncthreads();
    mx = fmaxf(fmaxf(red[0], red[1]), fmaxf(red[2], red[3]));
    __syncthreads();

    float t[4];
    float sum = 0.0f;
#pragma unroll
    for (int i = 0; i < 4; ++i) {
        t[i] = __expf(e[i] - mx) * mask[b * 1024 + tid + i * 256];
        sum += t[i];
    }
#pragma unroll
    for (int off = 1; off < 64; off <<= 1) sum += __shfl_xor(sum, off);
    if (lane == 0) red[wv] = sum;
    __syncthreads();
    sum = red[0] + red[1] + red[2] + red[3];

    float inv = 1.0f / sum;
#pragma unroll
    for (int i = 0; i < 4; ++i) alpha[b * 1024 + tid + i * 256] = t[i] * inv;
}

// ---------------------------------------------------------------------------
// Kernel 4: context[b][e] = sum_s alpha[b][s] * enc[b][s][e]  (f32, HBM-bound)
// grid (16 s-chunks, 32 b), block 256, float4 per thread, atomic accumulate.
__global__ __launch_bounds__(256) void context_kernel(const float* __restrict__ enc,
                                                      const float* __restrict__ alpha,
                                                      float* __restrict__ ctx) {
    int b = blockIdx.y;
    int sc = blockIdx.x;
    int tid = threadIdx.x;
    int e = tid * 4;
    const float* ep = enc + ((size_t)b * 1024 + sc * 64) * 1024 + e;
    const float* ap = alpha + b * 1024 + sc * 64;
    float a0 = 0.f, a1 = 0.f, a2 = 0.f, a3 = 0.f;
#pragma unroll 4
    for (int s = 0; s < 64; ++s) {
        float a = ap[s];
        f32x4 v = *(const f32x4*)(ep + (size_t)s * 1024);
        a0 += a * v[0]; a1 += a * v[1]; a2 += a * v[2]; a3 += a * v[3];
    }
    float* o = ctx + (size_t)b * 1024 + e;
    atomicAdd(o + 0, a0);
    atomicAdd(o + 1, a1);
    atomicAdd(o + 2, a2);
    atomicAdd(o + 3, a3);
}

// ---------------------------------------------------------------------------
extern "C" void kernel_launch(void* const* d_in, const int* in_sizes, int n_in,
                              void* d_out, int out_size, void* d_ws, size_t ws_size,
                              hipStream_t stream) {
    const float* dec_state = (const float*)d_in[0];   // [32,1024]
    const float* enc       = (const float*)d_in[1];   // [32,1024,1024]
    const float* mask      = (const float*)d_in[2];   // [32,1024]
    const float* W_enc     = (const float*)d_in[3];   // [1024,1024]
    const float* b_enc     = (const float*)d_in[4];   // [1024]
    const float* W_dec     = (const float*)d_in[5];   // [1024,1024]
    const float* w_attn    = (const float*)d_in[6];   // [1024]

    float* out   = (float*)d_out;
    float* ctx   = out;            // [32,1024]
    float* alpha = out + 32768;    // [32,1024]

    char* ws = (char*)d_ws;
    float* dec_full        = (float*)ws;               // 128 KB
    float* energy          = (float*)(ws + (128 << 10)); // 128 KB
    unsigned short* Wbf    = (unsigned short*)(ws + (256 << 10)); // 2 MB

    // ws/out are re-poisoned before every timed launch: zero accumulators.
    hipMemsetAsync(energy, 0, 32768 * sizeof(float), stream);
    hipMemsetAsync(ctx, 0, 32768 * sizeof(float), stream);

    cast_w_kernel<<<1024, 256, 0, stream>>>(W_enc, Wbf);
    dec_full_kernel<<<dim3(16, 32), 256, 0, stream>>>(dec_state, W_dec, b_enc, dec_full);
    energy_gemm<<<2048, 256, 0, stream>>>(enc, Wbf, dec_full, w_attn, energy);
    softmax_mask_kernel<<<32, 256, 0, stream>>>(energy, mask, alpha);
    context_kernel<<<dim3(16, 32), 256, 0, stream>>>(enc, alpha, ctx);
}

// Round 3
// 352.621 us; speedup vs baseline: 1.0530x; 1.0530x over previous
//
#include <hip/hip_runtime.h>
#include <hip/hip_bf16.h>

// Problem constants (match reference)
#define BB 32
#define SS 1024
#define EE 1024
#define AA 1024
// M = BB*SS = 32768

typedef __attribute__((ext_vector_type(8))) short short8;
typedef __attribute__((ext_vector_type(8))) unsigned short ushort8;
typedef __attribute__((ext_vector_type(4))) float f32x4;

__device__ inline unsigned short f2bf(float f) {
    __hip_bfloat16 h = __float2bfloat16(f);
    union { __hip_bfloat16 h; unsigned short s; } u;
    u.h = h;
    return u.s;
}

__device__ inline float fast_tanh(float x) {
    float e2 = __expf(2.0f * x);
    return 1.0f - 2.0f * __builtin_amdgcn_rcpf(e2 + 1.0f);
}

__device__ inline void gload_lds16(const unsigned short* g, unsigned short* l) {
    __builtin_amdgcn_global_load_lds((const __attribute__((address_space(1))) void*)g,
                                     (__attribute__((address_space(3))) void*)l, 16, 0, 0);
}

// ---------------------------------------------------------------------------
// cast W_enc (f32 [A][E]) -> bf16 ws copy. 1M elems, 4/thread.
__global__ __launch_bounds__(256) void cast_w_kernel(const float* __restrict__ W,
                                                     unsigned short* __restrict__ Wbf) {
    int i = (blockIdx.x * 256 + threadIdx.x) * 4;
    f32x4 v = *(const f32x4*)(W + i);
    union { unsigned short s[4]; unsigned long long q; } u;
    u.s[0] = f2bf(v[0]); u.s[1] = f2bf(v[1]); u.s[2] = f2bf(v[2]); u.s[3] = f2bf(v[3]);
    *(unsigned long long*)(Wbf + i) = u.q;
}

// cast enc (f32, 32M elems) -> bf16 ws copy. 8/thread, 16384 blocks.
__global__ __launch_bounds__(256) void cast_enc_kernel(const float* __restrict__ E,
                                                       unsigned short* __restrict__ Eb) {
    size_t i = ((size_t)blockIdx.x * 256 + threadIdx.x) * 8;
    f32x4 a = *(const f32x4*)(E + i);
    f32x4 b = *(const f32x4*)(E + i + 4);
    ushort8 v;
#pragma unroll
    for (int j = 0; j < 4; ++j) { v[j] = f2bf(a[j]); v[j + 4] = f2bf(b[j]); }
    *(ushort8*)(Eb + i) = v;
}

// ---------------------------------------------------------------------------
// dec_full[b][a] = sum_d dec_state[b][d]*W_dec[a][d] + b_enc[a]
__global__ __launch_bounds__(256) void dec_full_kernel(const float* __restrict__ dec_state,
                                                       const float* __restrict__ W_dec,
                                                       const float* __restrict__ b_enc,
                                                       float* __restrict__ dec_full) {
    int tid = threadIdx.x;
    int a = blockIdx.x * 64 + (tid >> 2);
    int q = tid & 3;
    int b = blockIdx.y;
    const float* wrow = W_dec + (size_t)a * 1024;
    const float* xrow = dec_state + (size_t)b * 1024;
    float acc = 0.0f;
#pragma unroll 8
    for (int i = 0; i < 64; ++i) {
        int d = q * 4 + i * 16;
        f32x4 w = *(const f32x4*)(wrow + d);
        f32x4 x = *(const f32x4*)(xrow + d);
        acc += w[0] * x[0] + w[1] * x[1] + w[2] * x[2] + w[3] * x[3];
    }
    acc += __shfl_xor(acc, 1);
    acc += __shfl_xor(acc, 2);
    if (q == 0) dec_full[(size_t)b * 1024 + a] = acc + b_enc[a];
}

// ---------------------------------------------------------------------------
// FAST PATH energy GEMM (m97 structure): bf16 A (pre-cast enc) and B (W_enc),
// global_load_lds width-16 staging, BM=BN=128, BK=64, 4 waves (2x2), 4x4 frags.
// Writes per-(n-block) partial energies: energy_p[bc][m] (no atomics).
__global__ __launch_bounds__(256) void energy_gemm2(const unsigned short* __restrict__ encb,
                                                    const unsigned short* __restrict__ Wbf,
                                                    const float* __restrict__ dec_full,
                                                    const float* __restrict__ w_attn,
                                                    float* __restrict__ energy_p) {
    __shared__ unsigned short As[128 * 64];
    __shared__ unsigned short Bs[128 * 64];

    // XCD swizzle: id%8 = XCD (round-robin dispatch). Each XCD walks its
    // row-panels sequentially with the 8 N-blocks of a panel adjacent ->
    // resident A working set ~3MB < 4MB per-XCD L2.
    int id = blockIdx.x;                 // 2048 = 256 row-panels x 8 col-blocks
    int r = id & 7, q = id >> 3;
    int br = ((q >> 3) << 3) | r;        // row-panel
    int bc = q & 7;                      // col-block
    int m0 = br * 128, n0 = bc * 128;

    int tid = threadIdx.x;
    int lane = tid & 63, w = tid >> 6;
    int wr = w >> 1, wc = w & 1;
    int l15 = lane & 15, lg = lane >> 4;

    // staging: thread covers row tid/8 (+32 per issue), 16B k-chunk tid%8
    int srow = tid >> 3;                 // 0..31
    int skc = tid & 7;                   // x8 bf16 elems
    const unsigned short* ga = encb + (size_t)(m0 + srow) * 1024 + skc * 8;
    const unsigned short* gb = Wbf + (size_t)(n0 + srow) * 1024 + skc * 8;
    unsigned short* la = As + srow * 64 + skc * 8;   // byte off = tid*16 (linear)
    unsigned short* lb = Bs + srow * 64 + skc * 8;

    f32x4 acc[4][4] = {};

    for (int k0 = 0; k0 < 1024; k0 += 64) {
#pragma unroll
        for (int i = 0; i < 4; ++i) {
            gload_lds16(ga + (size_t)i * 32 * 1024 + k0, la + i * 32 * 64);
            gload_lds16(gb + (size_t)i * 32 * 1024 + k0, lb + i * 32 * 64);
        }
        __syncthreads();                 // drains vmcnt before barrier
#pragma unroll
        for (int kk = 0; kk < 2; ++kk) {
            short8 af[4], bfr[4];
#pragma unroll
            for (int mi = 0; mi < 4; ++mi)
                af[mi] = *(const short8*)&As[(wr * 64 + mi * 16 + l15) * 64 + kk * 32 + lg * 8];
#pragma unroll
            for (int ni = 0; ni < 4; ++ni)
                bfr[ni] = *(const short8*)&Bs[(wc * 64 + ni * 16 + l15) * 64 + kk * 32 + lg * 8];
#pragma unroll
            for (int mi = 0; mi < 4; ++mi)
#pragma unroll
                for (int ni = 0; ni < 4; ++ni)
                    acc[mi][ni] = __builtin_amdgcn_mfma_f32_16x16x32_bf16(
                        af[mi], bfr[ni], acc[mi][ni], 0, 0, 0);
        }
        __syncthreads();
    }

    // Epilogue: tanh(acc + dec_full)*w_attn, reduce over this block's 128 n.
    int b = m0 >> 10;                    // batch constant per block
    float wv[4], dv[4];
#pragma unroll
    for (int ni = 0; ni < 4; ++ni) {
        int n = n0 + wc * 64 + ni * 16 + l15;
        wv[ni] = w_attn[n];
        dv[ni] = dec_full[(size_t)b * 1024 + n];
    }
    float parr[4][4];
#pragma unroll
    for (int mi = 0; mi < 4; ++mi) {
#pragma unroll
        for (int rr = 0; rr < 4; ++rr) {
            float p = 0.0f;
#pragma unroll
            for (int ni = 0; ni < 4; ++ni)
                p += fast_tanh(acc[mi][ni][rr] + dv[ni]) * wv[ni];
            p += __shfl_xor(p, 1);
            p += __shfl_xor(p, 2);
            p += __shfl_xor(p, 4);
            p += __shfl_xor(p, 8);
            parr[mi][rr] = p;            // valid on l15==0 lanes
        }
    }
    // combine the two wc-halves via LDS (As is free), then one store per m.
    float* sm = (float*)As;
    if (wc == 0 && l15 == 0) {
#pragma unroll
        for (int mi = 0; mi < 4; ++mi)
#pragma unroll
            for (int rr = 0; rr < 4; ++rr)
                sm[wr * 64 + mi * 16 + lg * 4 + rr] = parr[mi][rr];
    }
    __syncthreads();
    if (wc == 1 && l15 == 0) {
#pragma unroll
        for (int mi = 0; mi < 4; ++mi)
#pragma unroll
            for (int rr = 0; rr < 4; ++rr) {
                int ml = wr * 64 + mi * 16 + lg * 4 + rr;
                energy_p[(size_t)bc * 32768 + m0 + ml] = parr[mi][rr] + sm[ml];
            }
    }
}

// ---------------------------------------------------------------------------
// FALLBACK energy GEMM (round-2 proven path; used when ws is small).
__global__ __launch_bounds__(256) void energy_gemm(const float* __restrict__ enc,
                                                   const unsigned short* __restrict__ Wbf,
                                                   const float* __restrict__ dec_full,
                                                   const float* __restrict__ w_attn,
                                                   float* __restrict__ energy) {
    __shared__ unsigned short As[128 * 32];
    __shared__ unsigned short Bs[128 * 32];

    int id = blockIdx.x;
    int wid = (id & 7) * 256 + (id >> 3);
    int br = wid >> 3, bc = wid & 7;
    int m0 = br * 128, n0 = bc * 128;

    int tid = threadIdx.x;
    int lane = tid & 63, w = tid >> 6;
    int wr = w >> 1, wc = w & 1;
    int l15 = lane & 15, lg = lane >> 4;

    f32x4 acc[4][4] = {};

    int srow = tid >> 1;
    int shalf = tid & 1;
    const float* encp = enc + (size_t)(m0 + srow) * 1024 + shalf * 16;
    const unsigned short* wbp = Wbf + (size_t)(n0 + srow) * 1024 + shalf * 16;
    unsigned short* asw = &As[srow * 32 + shalf * 16];
    unsigned short* bsw = &Bs[srow * 32 + shalf * 16];

    for (int k0 = 0; k0 < 1024; k0 += 32) {
        f32x4 t0 = *(const f32x4*)(encp + k0);
        f32x4 t1 = *(const f32x4*)(encp + k0 + 4);
        f32x4 t2 = *(const f32x4*)(encp + k0 + 8);
        f32x4 t3 = *(const f32x4*)(encp + k0 + 12);
        ushort8 wb0 = *(const ushort8*)(wbp + k0);
        ushort8 wb1 = *(const ushort8*)(wbp + k0 + 8);

        __syncthreads();
        ushort8 pa, pb;
#pragma unroll
        for (int j = 0; j < 4; ++j) {
            pa[j]     = f2bf(t0[j]);
            pa[j + 4] = f2bf(t1[j]);
            pb[j]     = f2bf(t2[j]);
            pb[j + 4] = f2bf(t3[j]);
        }
        *(ushort8*)asw       = pa;
        *(ushort8*)(asw + 8) = pb;
        *(ushort8*)bsw       = wb0;
        *(ushort8*)(bsw + 8) = wb1;
        __syncthreads();

        short8 af[4], bfr[4];
#pragma unroll
        for (int mi = 0; mi < 4; ++mi)
            af[mi] = *(const short8*)&As[(wr * 64 + mi * 16 + l15) * 32 + lg * 8];
#pragma unroll
        for (int ni = 0; ni < 4; ++ni)
            bfr[ni] = *(const short8*)&Bs[(wc * 64 + ni * 16 + l15) * 32 + lg * 8];
#pragma unroll
        for (int mi = 0; mi < 4; ++mi)
#pragma unroll
            for (int ni = 0; ni < 4; ++ni)
                acc[mi][ni] = __builtin_amdgcn_mfma_f32_16x16x32_bf16(
                    af[mi], bfr[ni], acc[mi][ni], 0, 0, 0);
    }

    int b = m0 >> 10;
    float wv[4], dv[4];
#pragma unroll
    for (int ni = 0; ni < 4; ++ni) {
        int n = n0 + wc * 64 + ni * 16 + l15;
        wv[ni] = w_attn[n];
        dv[ni] = dec_full[(size_t)b * 1024 + n];
    }
#pragma unroll
    for (int mi = 0; mi < 4; ++mi) {
#pragma unroll
        for (int rr = 0; rr < 4; ++rr) {
            float p = 0.0f;
#pragma unroll
            for (int ni = 0; ni < 4; ++ni)
                p += fast_tanh(acc[mi][ni][rr] + dv[ni]) * wv[ni];
            p += __shfl_xor(p, 1);
            p += __shfl_xor(p, 2);
            p += __shfl_xor(p, 4);
            p += __shfl_xor(p, 8);
            if (l15 == 0) {
                int m = m0 + wr * 64 + mi * 16 + lg * 4 + rr;
                atomicAdd(&energy[m], p);
            }
        }
    }
}

// ---------------------------------------------------------------------------
// masked softmax + renorm, summing 8 per-bc energy partials (fast path).
__global__ __launch_bounds__(256) void softmax_mask8_kernel(const float* __restrict__ energy_p,
                                                            const float* __restrict__ mask,
                                                            float* __restrict__ alpha) {
    int b = blockIdx.x;
    int tid = threadIdx.x;
    int lane = tid & 63, wv = tid >> 6;
    __shared__ float red[4];

    float e[4];
#pragma unroll
    for (int i = 0; i < 4; ++i) {
        float s = 0.0f;
#pragma unroll
        for (int j = 0; j < 8; ++j)
            s += energy_p[(size_t)j * 32768 + b * 1024 + tid + i * 256];
        e[i] = s;
    }

    float mx = fmaxf(fmaxf(e[0], e[1]), fmaxf(e[2], e[3]));
#pragma unroll
    for (int off = 1; off < 64; off <<= 1) mx = fmaxf(mx, __shfl_xor(mx, off));
    if (lane == 0) red[wv] = mx;
    __syncthreads();
    mx = fmaxf(fmaxf(red[0], red[1]), fmaxf(red[2], red[3]));
    __syncthreads();

    float t[4];
    float sum = 0.0f;
#pragma unroll
    for (int i = 0; i < 4; ++i) {
        t[i] = __expf(e[i] - mx) * mask[b * 1024 + tid + i * 256];
        sum += t[i];
    }
#pragma unroll
    for (int off = 1; off < 64; off <<= 1) sum += __shfl_xor(sum, off);
    if (lane == 0) red[wv] = sum;
    __syncthreads();
    sum = red[0] + red[1] + red[2] + red[3];

    float inv = 1.0f / sum;
#pragma unroll
    for (int i = 0; i < 4; ++i) alpha[b * 1024 + tid + i * 256] = t[i] * inv;
}

// fallback softmax (single energy buffer)
__global__ __launch_bounds__(256) void softmax_mask_kernel(const float* __restrict__ energy,
                                                           const float* __restrict__ mask,
                                                           float* __restrict__ alpha) {
    int b = blockIdx.x;
    int tid = threadIdx.x;
    int lane = tid & 63, wv = tid >> 6;
    __shared__ float red[4];

    float e[4];
#pragma unroll
    for (int i = 0; i < 4; ++i) e[i] = energy[b * 1024 + tid + i * 256];

    float mx = fmaxf(fmaxf(e[0], e[1]), fmaxf(e[2], e[3]));
#pragma unroll
    for (int off = 1; off < 64; off <<= 1) mx = fmaxf(mx, __shfl_xor(mx, off));
    if (lane == 0) red[wv] = mx;
    __syncthreads();
    mx = fmaxf(fmaxf(red[0], red[1]), fmaxf(red[2], red[3]));
    __syncthreads();

    float t[4];
    float sum = 0.0f;
#pragma unroll
    for (int i = 0; i < 4; ++i) {
        t[i] = __expf(e[i] - mx) * mask[b * 1024 + tid + i * 256];
        sum += t[i];
    }
#pragma unroll
    for (int off = 1; off < 64; off <<= 1) sum += __shfl_xor(sum, off);
    if (lane == 0) red[wv] = sum;
    __syncthreads();
    sum = red[0] + red[1] + red[2] + red[3];

    float inv = 1.0f / sum;
#pragma unroll
    for (int i = 0; i < 4; ++i) alpha[b * 1024 + tid + i * 256] = t[i] * inv;
}

// ---------------------------------------------------------------------------
// context, atomic-free: partials to ws, then reduce.
__global__ __launch_bounds__(256) void context_partial_kernel(const float* __restrict__ enc,
                                                              const float* __restrict__ alpha,
                                                              float* __restrict__ cp) {
    int b = blockIdx.y;
    int sc = blockIdx.x;
    int tid = threadIdx.x;
    int e = tid * 4;
    const float* ep = enc + ((size_t)b * 1024 + sc * 64) * 1024 + e;
    const float* ap = alpha + b * 1024 + sc * 64;
    float a0 = 0.f, a1 = 0.f, a2 = 0.f, a3 = 0.f;
#pragma unroll 4
    for (int s = 0; s < 64; ++s) {
        float a = ap[s];
        f32x4 v = *(const f32x4*)(ep + (size_t)s * 1024);
        a0 += a * v[0]; a1 += a * v[1]; a2 += a * v[2]; a3 += a * v[3];
    }
    f32x4 o; o[0] = a0; o[1] = a1; o[2] = a2; o[3] = a3;
    *(f32x4*)(cp + ((size_t)sc * 32 + b) * 1024 + e) = o;
}

__global__ __launch_bounds__(256) void context_reduce_kernel(const float* __restrict__ cp,
                                                             float* __restrict__ ctx) {
    int b = blockIdx.x;
    int e = threadIdx.x * 4;
    f32x4 s = {};
#pragma unroll
    for (int sc = 0; sc < 16; ++sc) {
        f32x4 v = *(const f32x4*)(cp + ((size_t)sc * 32 + b) * 1024 + e);
        s[0] += v[0]; s[1] += v[1]; s[2] += v[2]; s[3] += v[3];
    }
    *(f32x4*)(ctx + (size_t)b * 1024 + e) = s;
}

// fallback context (atomics into ctx)
__global__ __launch_bounds__(256) void context_kernel(const float* __restrict__ enc,
                                                      const float* __restrict__ alpha,
                                                      float* __restrict__ ctx) {
    int b = blockIdx.y;
    int sc = blockIdx.x;
    int tid = threadIdx.x;
    int e = tid * 4;
    const float* ep = enc + ((size_t)b * 1024 + sc * 64) * 1024 + e;
    const float* ap = alpha + b * 1024 + sc * 64;
    float a0 = 0.f, a1 = 0.f, a2 = 0.f, a3 = 0.f;
#pragma unroll 4
    for (int s = 0; s < 64; ++s) {
        float a = ap[s];
        f32x4 v = *(const f32x4*)(ep + (size_t)s * 1024);
        a0 += a * v[0]; a1 += a * v[1]; a2 += a * v[2]; a3 += a * v[3];
    }
    float* o = ctx + (size_t)b * 1024 + e;
    atomicAdd(o + 0, a0);
    atomicAdd(o + 1, a1);
    atomicAdd(o + 2, a2);
    atomicAdd(o + 3, a3);
}

// ---------------------------------------------------------------------------
extern "C" void kernel_launch(void* const* d_in, const int* in_sizes, int n_in,
                              void* d_out, int out_size, void* d_ws, size_t ws_size,
                              hipStream_t stream) {
    const float* dec_state = (const float*)d_in[0];   // [32,1024]
    const float* enc       = (const float*)d_in[1];   // [32,1024,1024]
    const float* mask      = (const float*)d_in[2];   // [32,1024]
    const float* W_enc     = (const float*)d_in[3];   // [1024,1024]
    const float* b_enc     = (const float*)d_in[4];   // [1024]
    const float* W_dec     = (const float*)d_in[5];   // [1024,1024]
    const float* w_attn    = (const float*)d_in[6];   // [1024]

    float* out   = (float*)d_out;
    float* ctx   = out;            // [32,1024]
    float* alpha = out + 32768;    // [32,1024]

    char* ws = (char*)d_ws;
    // fast-path ws layout
    float* dec_full      = (float*)ws;                        // 128 KB @ 0
    float* energy_p      = (float*)(ws + 131072);             // 1 MB
    unsigned short* Wbf  = (unsigned short*)(ws + 1179648);   // 2 MB
    float* cp            = (float*)(ws + 3276800);            // 2 MB
    unsigned short* encb = (unsigned short*)(ws + 5373952);   // 64 MB
    const size_t WS_FAST = 5373952 + 67108864;                // ~69.2 MB

    if (ws_size >= WS_FAST) {
        cast_w_kernel<<<1024, 256, 0, stream>>>(W_enc, Wbf);
        cast_enc_kernel<<<16384, 256, 0, stream>>>(enc, encb);
        dec_full_kernel<<<dim3(16, 32), 256, 0, stream>>>(dec_state, W_dec, b_enc, dec_full);
        energy_gemm2<<<2048, 256, 0, stream>>>(encb, Wbf, dec_full, w_attn, energy_p);
        softmax_mask8_kernel<<<32, 256, 0, stream>>>(energy_p, mask, alpha);
        context_partial_kernel<<<dim3(16, 32), 256, 0, stream>>>(enc, alpha, cp);
        context_reduce_kernel<<<32, 256, 0, stream>>>(cp, ctx);
    } else {
        // round-2 proven fallback (small ws): energy @128KB, Wbf @256KB
        float* energy       = (float*)(ws + (128 << 10));
        unsigned short* Wb2 = (unsigned short*)(ws + (256 << 10));
        hipMemsetAsync(energy, 0, 32768 * sizeof(float), stream);
        hipMemsetAsync(ctx, 0, 32768 * sizeof(float), stream);
        cast_w_kernel<<<1024, 256, 0, stream>>>(W_enc, Wb2);
        dec_full_kernel<<<dim3(16, 32), 256, 0, stream>>>(dec_state, W_dec, b_enc, dec_full);
        energy_gemm<<<2048, 256, 0, stream>>>(enc, Wb2, dec_full, w_attn, energy);
        softmax_mask_kernel<<<32, 256, 0, stream>>>(energy, mask, alpha);
        context_kernel<<<dim3(16, 32), 256, 0, stream>>>(enc, alpha, ctx);
    }
}